// Round 2
// baseline (474.552 us; speedup 1.0000x reference)
//
#include <hip/hip_runtime.h>

// SurfSageEncoder: 3x SAGEConv(mean) + linear head, fp32.
// N=50000 nodes, E=600000 edges, D: 128 -> 128 -> 128 -> 64 -> 64.
//
// Strategy:
//   1. Build CSR (edges grouped by dst) once per call: histogram -> scan -> fill.
//   2. Layers 1-2: k_agg (one wave per node, register accumulation, mean) then
//      k_linear (2-phase LDS-tiled fp32 GEMM: mean@Wl^T + x@Wr^T + b, ReLU).
//   3. Layer 3: transform-BEFORE-aggregate (mean is linear): one dual GEMM
//      producing P=h@Wl3^T and Q=h@Wr3^T+bl3, then 64-dim mean-agg of P plus Q
//      (halves layer-3 gather traffic). Head: single-phase k_linear.
// edge_index arrives as int32 per harness convention.

#define BLK 256

// ---------------- CSR build ----------------

__global__ __launch_bounds__(BLK) void k_hist(const int* __restrict__ dst,
                                              int* __restrict__ deg, int E) {
  int i = blockIdx.x * BLK + threadIdx.x;
  int stride = gridDim.x * BLK;
  for (; i < E; i += stride) atomicAdd(&deg[dst[i]], 1);
}

// Block-level exclusive scan: each block handles 1024 elems (4/thread).
__global__ __launch_bounds__(BLK) void k_scan1(const int* __restrict__ deg,
                                               int* __restrict__ offs,
                                               int* __restrict__ bsums, int n) {
  __shared__ int lds[BLK];
  int t = threadIdx.x;
  int base = blockIdx.x * 1024 + t * 4;
  int v0 = (base + 0 < n) ? deg[base + 0] : 0;
  int v1 = (base + 1 < n) ? deg[base + 1] : 0;
  int v2 = (base + 2 < n) ? deg[base + 2] : 0;
  int v3 = (base + 3 < n) ? deg[base + 3] : 0;
  int s = v0 + v1 + v2 + v3;
  lds[t] = s;
  __syncthreads();
  for (int off = 1; off < BLK; off <<= 1) {
    int x = 0;
    if (t >= off) x = lds[t - off];
    __syncthreads();
    if (t >= off) lds[t] += x;
    __syncthreads();
  }
  int excl = lds[t] - s;  // exclusive prefix within block
  if (base + 0 < n) offs[base + 0] = excl;
  if (base + 1 < n) offs[base + 1] = excl + v0;
  if (base + 2 < n) offs[base + 2] = excl + v0 + v1;
  if (base + 3 < n) offs[base + 3] = excl + v0 + v1 + v2;
  if (t == BLK - 1) bsums[blockIdx.x] = lds[BLK - 1];
}

__global__ void k_scan2(int* __restrict__ bsums, int nb) {
  if (blockIdx.x == 0 && threadIdx.x == 0) {
    int acc = 0;
    for (int i = 0; i < nb; ++i) { int v = bsums[i]; bsums[i] = acc; acc += v; }
  }
}

__global__ __launch_bounds__(BLK) void k_scan3(int* __restrict__ offs,
                                               const int* __restrict__ bsums,
                                               int* __restrict__ cursor, int n, int E) {
  int i = blockIdx.x * BLK + threadIdx.x;
  if (i < n) {
    int o = offs[i] + bsums[i >> 10];
    offs[i] = o;
    cursor[i] = o;
  }
  if (i == 0) offs[n] = E;
}

__global__ __launch_bounds__(BLK) void k_fill(const int* __restrict__ src,
                                              const int* __restrict__ dst,
                                              int* __restrict__ cursor,
                                              int* __restrict__ csr, int E) {
  int i = blockIdx.x * BLK + threadIdx.x;
  int stride = gridDim.x * BLK;
  for (; i < E; i += stride) {
    int p = atomicAdd(&cursor[dst[i]], 1);
    csr[p] = src[i];
  }
}

// ---------------- mean aggregation: one wave per node, D=128 ----------------

__global__ __launch_bounds__(BLK) void k_agg(const float* __restrict__ in,
                                             const int* __restrict__ offs,
                                             const int* __restrict__ csr,
                                             float* __restrict__ outmean, int n) {
  int wid = (blockIdx.x * BLK + threadIdx.x) >> 6;  // one wave per node
  int lane = threadIdx.x & 63;
  if (wid >= n) return;
  int beg = offs[wid], end = offs[wid + 1];
  const float2* in2 = (const float2*)in;  // 64 lanes x float2 = 128 feats
  float ax = 0.f, ay = 0.f;
  int e = beg;
  for (; e + 1 < end; e += 2) {  // unroll 2: overlap the two row loads
    int s0 = csr[e], s1 = csr[e + 1];
    float2 a = in2[s0 * 64 + lane];
    float2 b = in2[s1 * 64 + lane];
    ax += a.x; ay += a.y;
    ax += b.x; ay += b.y;
  }
  if (e < end) {
    int s = csr[e];
    float2 a = in2[s * 64 + lane];
    ax += a.x; ay += a.y;
  }
  int d = end - beg;
  float inv = 1.0f / (float)(d > 0 ? d : 1);
  float2 r; r.x = ax * inv; r.y = ay * inv;
  ((float2*)outmean)[wid * 64 + lane] = r;
}

// mean-agg of 64-dim P (cols 0..63 of PQ, row stride 128) plus Q (cols 64..127).
// outv[node][0:64] = mean_{s in N(node)} PQ[s][0:64] + PQ[node][64:128]
__global__ __launch_bounds__(BLK) void k_agg_add(const float* __restrict__ PQ,
                                                 const int* __restrict__ offs,
                                                 const int* __restrict__ csr,
                                                 float* __restrict__ outv, int n) {
  int wid = (blockIdx.x * BLK + threadIdx.x) >> 6;  // one wave per node
  int lane = threadIdx.x & 63;
  if (wid >= n) return;
  int beg = offs[wid], end = offs[wid + 1];
  float a = 0.f;
  int e = beg;
  for (; e + 1 < end; e += 2) {
    int s0 = csr[e], s1 = csr[e + 1];
    a += PQ[s0 * 128 + lane];
    a += PQ[s1 * 128 + lane];
  }
  if (e < end) a += PQ[csr[e] * 128 + lane];
  int d = end - beg;
  float inv = 1.0f / (float)(d > 0 ? d : 1);
  outv[wid * 64 + lane] = a * inv + PQ[wid * 128 + 64 + lane];
}

// ---------------- fused linear: out = A0@W0^T (+ A1@W1^T) + bias, opt ReLU ----
// W is [COLS][K] row-major (torch-style). Block tile: 64 rows x COLS cols.
// KT=32 K-slab staged in LDS; A-tile padded to stride 36 floats (16B-aligned,
// broadcast reads conflict-free).

template <int COLS, int PHASES, bool RELU>
__global__ __launch_bounds__(BLK) void k_linear(
    const float* __restrict__ A0, const float* __restrict__ W0, int K0,
    const float* __restrict__ A1, const float* __restrict__ W1, int K1,
    const float* __restrict__ bias, float* __restrict__ out, int M) {
  constexpr int KT = 32;
  constexpr int TC = COLS / 4;   // thread-cols (32 or 16)
  constexpr int TR = BLK / TC;   // thread-rows (8 or 16)
  constexpr int RPT = 64 / TR;   // rows per thread (8 or 4)
  constexpr int AS = KT + 4;     // 36 floats: 144B rows, 16B-aligned, bank-spread

  __shared__ float As[64 * AS];
  __shared__ float Bt[KT * COLS];

  int tid = threadIdx.x;
  int tc = tid % TC, tr = tid / TC;
  int j0 = tc * 4;
  int rbase = tr * RPT;
  int growbase = blockIdx.x * 64;

  float4 acc[RPT];
#pragma unroll
  for (int rr = 0; rr < RPT; ++rr) acc[rr] = make_float4(0.f, 0.f, 0.f, 0.f);

#pragma unroll
  for (int ph = 0; ph < PHASES; ++ph) {
    const float* A = (ph == 0) ? A0 : A1;
    const float* W = (ph == 0) ? W0 : W1;
    int K = (ph == 0) ? K0 : K1;
    for (int k0 = 0; k0 < K; k0 += KT) {
      // stage A-tile: 64 rows x 32 k = 512 float4
#pragma unroll
      for (int t = tid; t < 512; t += BLK) {
        int row = t >> 3, f4 = (t & 7) * 4;
        int gr = growbase + row;
        float4 v = make_float4(0.f, 0.f, 0.f, 0.f);
        if (gr < M) v = *(const float4*)&A[gr * K + k0 + f4];
        *(float4*)&As[row * AS + f4] = v;
      }
      // stage B-tile transposed: Bt[k][j] = W[j][k0+k]
#pragma unroll
      for (int t = tid; t < COLS * 8; t += BLK) {
        int j = t >> 3;
        int kk = (t & 7) * 4;
        float4 w = *(const float4*)&W[j * K + k0 + kk];
        Bt[(kk + 0) * COLS + j] = w.x;
        Bt[(kk + 1) * COLS + j] = w.y;
        Bt[(kk + 2) * COLS + j] = w.z;
        Bt[(kk + 3) * COLS + j] = w.w;
      }
      __syncthreads();
#pragma unroll
      for (int kk = 0; kk < KT; kk += 4) {
        float4 a4[RPT];
#pragma unroll
        for (int rr = 0; rr < RPT; ++rr)
          a4[rr] = *(const float4*)&As[(rbase + rr) * AS + kk];
#pragma unroll
        for (int dk = 0; dk < 4; ++dk) {
          float4 b = *(const float4*)&Bt[(kk + dk) * COLS + j0];
#pragma unroll
          for (int rr = 0; rr < RPT; ++rr) {
            float av = (dk == 0) ? a4[rr].x
                     : (dk == 1) ? a4[rr].y
                     : (dk == 2) ? a4[rr].z : a4[rr].w;
            acc[rr].x += av * b.x;
            acc[rr].y += av * b.y;
            acc[rr].z += av * b.z;
            acc[rr].w += av * b.w;
          }
        }
      }
      __syncthreads();
    }
  }

  float4 bv = *(const float4*)&bias[j0];
#pragma unroll
  for (int rr = 0; rr < RPT; ++rr) {
    int gr = growbase + rbase + rr;
    if (gr < M) {
      float4 o;
      o.x = acc[rr].x + bv.x;
      o.y = acc[rr].y + bv.y;
      o.z = acc[rr].z + bv.z;
      o.w = acc[rr].w + bv.w;
      if (RELU) {
        o.x = fmaxf(o.x, 0.f); o.y = fmaxf(o.y, 0.f);
        o.z = fmaxf(o.z, 0.f); o.w = fmaxf(o.w, 0.f);
      }
      *(float4*)&out[gr * COLS + j0] = o;
    }
  }
}

// Dual-output linear for layer 3: out[gr][j] = A@Wl3^T (j<64) | A@Wr3^T + bl3 (j>=64).
// Same tile structure as k_linear<128,1,false>, W row chosen per output column.
__global__ __launch_bounds__(BLK) void k_linear_dual(
    const float* __restrict__ A, const float* __restrict__ W0,
    const float* __restrict__ W1, const float* __restrict__ bias,
    float* __restrict__ out, int M) {
  constexpr int COLS = 128, KT = 32, K = 128;
  constexpr int TC = COLS / 4;   // 32
  constexpr int TR = BLK / TC;   // 8
  constexpr int RPT = 64 / TR;   // 8
  constexpr int AS = KT + 4;

  __shared__ float As[64 * AS];
  __shared__ float Bt[KT * COLS];

  int tid = threadIdx.x;
  int tc = tid % TC, tr = tid / TC;
  int j0 = tc * 4;
  int rbase = tr * RPT;
  int growbase = blockIdx.x * 64;

  float4 acc[RPT];
#pragma unroll
  for (int rr = 0; rr < RPT; ++rr) acc[rr] = make_float4(0.f, 0.f, 0.f, 0.f);

  for (int k0 = 0; k0 < K; k0 += KT) {
#pragma unroll
    for (int t = tid; t < 512; t += BLK) {
      int row = t >> 3, f4 = (t & 7) * 4;
      int gr = growbase + row;
      float4 v = make_float4(0.f, 0.f, 0.f, 0.f);
      if (gr < M) v = *(const float4*)&A[gr * K + k0 + f4];
      *(float4*)&As[row * AS + f4] = v;
    }
#pragma unroll
    for (int t = tid; t < COLS * 8; t += BLK) {
      int j = t >> 3;
      int kk = (t & 7) * 4;
      const float* Wrow = (j < 64) ? &W0[j * K] : &W1[(j - 64) * K];
      float4 w = *(const float4*)&Wrow[k0 + kk];
      Bt[(kk + 0) * COLS + j] = w.x;
      Bt[(kk + 1) * COLS + j] = w.y;
      Bt[(kk + 2) * COLS + j] = w.z;
      Bt[(kk + 3) * COLS + j] = w.w;
    }
    __syncthreads();
#pragma unroll
    for (int kk = 0; kk < KT; kk += 4) {
      float4 a4[RPT];
#pragma unroll
      for (int rr = 0; rr < RPT; ++rr)
        a4[rr] = *(const float4*)&As[(rbase + rr) * AS + kk];
#pragma unroll
      for (int dk = 0; dk < 4; ++dk) {
        float4 b = *(const float4*)&Bt[(kk + dk) * COLS + j0];
#pragma unroll
        for (int rr = 0; rr < RPT; ++rr) {
          float av = (dk == 0) ? a4[rr].x
                   : (dk == 1) ? a4[rr].y
                   : (dk == 2) ? a4[rr].z : a4[rr].w;
          acc[rr].x += av * b.x;
          acc[rr].y += av * b.y;
          acc[rr].z += av * b.z;
          acc[rr].w += av * b.w;
        }
      }
    }
    __syncthreads();
  }

  // bias only on the Q half (j >= 64)
  float4 bv = make_float4(0.f, 0.f, 0.f, 0.f);
  if (j0 >= 64) bv = *(const float4*)&bias[j0 - 64];
#pragma unroll
  for (int rr = 0; rr < RPT; ++rr) {
    int gr = growbase + rbase + rr;
    if (gr < M) {
      float4 o;
      o.x = acc[rr].x + bv.x;
      o.y = acc[rr].y + bv.y;
      o.z = acc[rr].z + bv.z;
      o.w = acc[rr].w + bv.w;
      *(float4*)&out[gr * COLS + j0] = o;
    }
  }
}

// ---------------- launch ----------------

extern "C" void kernel_launch(void* const* d_in, const int* in_sizes, int n_in,
                              void* d_out, int out_size, void* d_ws, size_t ws_size,
                              hipStream_t stream) {
  const float* x    = (const float*)d_in[0];
  const int*   edge = (const int*)d_in[1];
  const float* Wl1  = (const float*)d_in[2];
  const float* bl1  = (const float*)d_in[3];
  const float* Wr1  = (const float*)d_in[4];
  const float* Wl2  = (const float*)d_in[5];
  const float* bl2  = (const float*)d_in[6];
  const float* Wr2  = (const float*)d_in[7];
  const float* Wl3  = (const float*)d_in[8];
  const float* bl3  = (const float*)d_in[9];
  const float* Wr3  = (const float*)d_in[10];
  const float* Wreg = (const float*)d_in[11];
  const float* breg = (const float*)d_in[12];

  const int N = in_sizes[0] / 128;  // 50000
  const int E = in_sizes[1] / 2;    // 600000
  const int* src = edge;
  const int* dst = edge + E;

  // workspace carve-up (256B aligned)
  char* ws = (char*)d_ws;
  size_t off = 0;
  auto alloc = [&](size_t bytes) {
    void* p = ws + off;
    off = (off + bytes + 255) & ~(size_t)255;
    return p;
  };
  int*   deg    = (int*)alloc((size_t)N * 4);
  int*   offs   = (int*)alloc((size_t)(N + 1) * 4);
  int*   cursor = (int*)alloc((size_t)N * 4);
  int*   csr    = (int*)alloc((size_t)E * 4);
  int*   bsums  = (int*)alloc(256 * 4);
  float* mean   = (float*)alloc((size_t)N * 128 * 4);  // also PQ buffer in layer 3
  float* hA     = (float*)alloc((size_t)N * 128 * 4);
  float* hB     = (float*)alloc((size_t)N * 128 * 4);
  (void)ws_size;

  // --- CSR build ---
  hipMemsetAsync(deg, 0, (size_t)N * 4, stream);
  k_hist<<<2048, BLK, 0, stream>>>(dst, deg, E);
  int nb = (N + 1023) >> 10;  // 49
  k_scan1<<<nb, BLK, 0, stream>>>(deg, offs, bsums, N);
  k_scan2<<<1, 64, 0, stream>>>(bsums, nb);
  k_scan3<<<(N + BLK - 1) / BLK, BLK, 0, stream>>>(offs, bsums, cursor, N, E);
  k_fill<<<2048, BLK, 0, stream>>>(src, dst, cursor, csr, E);

  const int aggGrid = (N * 64 + BLK - 1) / BLK;  // one wave per node
  const int gemmGrid = (N + 63) / 64;

  // --- layer 1: h1 = relu(mean(x)@Wl1^T + x@Wr1^T + bl1) ---
  k_agg<<<aggGrid, BLK, 0, stream>>>(x, offs, csr, mean, N);
  k_linear<128, 2, true><<<gemmGrid, BLK, 0, stream>>>(
      mean, Wl1, 128, x, Wr1, 128, bl1, hA, N);

  // --- layer 2 ---
  k_agg<<<aggGrid, BLK, 0, stream>>>(hA, offs, csr, mean, N);
  k_linear<128, 2, true><<<gemmGrid, BLK, 0, stream>>>(
      mean, Wl2, 128, hA, Wr2, 128, bl2, hB, N);

  // --- layer 3 (transform-before-aggregate, no relu) ---
  // PQ = [hB@Wl3^T | hB@Wr3^T + bl3]; h3 = mean-agg(P) + Q
  k_linear_dual<<<gemmGrid, BLK, 0, stream>>>(hB, Wl3, Wr3, bl3, mean, N);
  k_agg_add<<<aggGrid, BLK, 0, stream>>>(mean, offs, csr, hA, N);

  // --- head: out = h3@Wreg^T + breg ---
  k_linear<64, 1, false><<<gemmGrid, BLK, 0, stream>>>(
      hA, Wreg, 64, (const float*)nullptr, (const float*)nullptr, 0, breg,
      (float*)d_out, N);
}